// Round 9
// baseline (55.785 us; speedup 1.0000x reference)
//
#include <hip/hip_runtime.h>
#include <hip/hip_bf16.h>

#define LAMBDA 0.75f
#define CMID 256
#define DOUT 4096

typedef __attribute__((ext_vector_type(8))) short bf16x8;   // MFMA A/B operand
typedef __attribute__((ext_vector_type(4))) float f32x4;    // MFMA C/D operand

static inline __device__ short f2bf(float f) {
    __hip_bfloat16 h = __float2bfloat16(f);
    short s; __builtin_memcpy(&s, &h, 2);
    return s;
}
static inline __device__ unsigned pack2(float lo, float hi) {
    unsigned a = (unsigned short)f2bf(lo);
    unsigned b = (unsigned short)f2bf(hi);
    return a | (b << 16);
}

// ---------------------------------------------------------------------------
// Fused conv3x3(p=1)+bias+relu+hardshrink+pool, implicit GEMM via MFMA.
// Round-9 change: occupancy + serial-chain attack (rounds 6-8 proved phase-3
// micro-opts are not the bottleneck; total was insensitive to them).
//   - 512-thread blocks, 4 output rows each -> 1024 blocks.
//   - wave owns 2 co-tiles (not 4): ~80 live regs -> launch_bounds(512,4)
//     = 16 waves/CU = 4 waves/SIMD (2x round-8), cap 128 VGPR, no spill.
//   - per-block {preamble -> stage -> barrier -> im2col -> barrier -> mfma}
//     chains halved in count, weight preamble amortized over 4 rows.
// Layout recap: im2col[g][col] uint4, conflict-free b128 reads (quarter-wave
// reads 256 contiguous bytes); k-slot map s=g*8+j identical on A and B sides
// (any HW k-bijection works); g<3: ci=g,ky=j/3,kx=j%3; g==3: j<3 ci=j tap(2,2),
// j>=3 zero-weight. Per-block partials, no atomics/memset.
// ---------------------------------------------------------------------------
__global__ __launch_bounds__(512, 4) void conv_pool_mfma(
    const float* __restrict__ x, const float* __restrict__ conv_w,
    const float* __restrict__ conv_b, float* __restrict__ part)
{
    __shared__ float raw[2448];           // [ci][r 0..5][idx 0..135], col=idx-4
    __shared__ uint4 im2col[4][512];      // [g][col] -> 8 bf16 k-slots, 32 KB

    const int bk = blockIdx.x;
    const int b  = bk >> 5;
    const int h0 = (bk & 31) * 4;
    const int t  = threadIdx.x;           // 0..511
    const int l  = t & 63;
    const int wv = t >> 6;                // wave 0..7
    const int lm = l & 15;
    const int g  = l >> 4;

    // ---- phase 1: stage raw x rows h0-1..h0+4 (zero-padded borders) ----
    for (int i = t; i < 2448; i += 512) {
        int ci  = i / 816;
        int rem = i - ci * 816;
        int r   = rem / 136;
        int idx = rem - r * 136;
        int hh  = h0 - 1 + r;
        int col = idx - 4;
        float v = 0.f;
        if ((unsigned)hh < 128u && (unsigned)col < 128u)
            v = x[(b * 3 + ci) * 16384 + hh * 128 + col];
        raw[i] = v;
    }

    // ---- weights as B-frags: wave wv owns co-tiles {2wv, 2wv+1} ----
    bf16x8 wfrag[2];
    f32x4  biasf[2], pool[2];
    #pragma unroll
    for (int c = 0; c < 2; ++c) {
        const int ct = wv * 2 + c;
        const int co = ct * 16 + lm;
        const float* wp = conv_w + co * 27;
        float av[8];
        if (g < 3) {
            #pragma unroll
            for (int j = 0; j < 8; ++j) av[j] = wp[g * 9 + j];
        } else {
            av[0] = wp[8]; av[1] = wp[17]; av[2] = wp[26];
            av[3] = av[4] = av[5] = av[6] = av[7] = 0.f;
        }
        #pragma unroll
        for (int j = 0; j < 8; ++j) wfrag[c][j] = f2bf(av[j]);
        const float bb = conv_b[co];
        biasf[c] = (f32x4){bb, bb, bb, bb};
        pool[c]  = (f32x4){0.f, 0.f, 0.f, 0.f};
    }

    __syncthreads();

    // ---- phase 2: build im2col; thread t = column (out_r = t>>7, px = t&127) ----
    {
        const int out_r = t >> 7;          // 0..3
        const int px    = t & 127;
        const float* r0 = raw + 0 * 816 + out_r * 136 + px + 3;
        const float* r1 = raw + 1 * 816 + out_r * 136 + px + 3;
        const float* r2 = raw + 2 * 816 + out_r * 136 + px + 3;
        uint4 w;
        w.x = pack2(r0[0],   r0[1]);   w.y = pack2(r0[2],   r0[136]);
        w.z = pack2(r0[137], r0[138]); w.w = pack2(r0[272], r0[273]);
        im2col[0][t] = w;
        w.x = pack2(r1[0],   r1[1]);   w.y = pack2(r1[2],   r1[136]);
        w.z = pack2(r1[137], r1[138]); w.w = pack2(r1[272], r1[273]);
        im2col[1][t] = w;
        w.x = pack2(r2[0],   r2[1]);   w.y = pack2(r2[2],   r2[136]);
        w.z = pack2(r2[137], r2[138]); w.w = pack2(r2[272], r2[273]);
        im2col[2][t] = w;
        w.x = pack2(r0[274], r1[274]); w.y = pack2(r2[274], 0.f);
        w.z = 0u;                      w.w = 0u;   // dead k-slots = 0
        im2col[3][t] = w;
    }

    __syncthreads();

    // ---- phase 3: 32 px-tiles x 2 co-tiles, 1-deep software pipeline ----
    f32x4 accP0, accP1;
    uint4 x_nxt;
    {
        const uint4 x0 = im2col[g][lm];
        x_nxt = im2col[g][16 + lm];
        bf16x8 xf; __builtin_memcpy(&xf, &x0, 16);
        accP0 = __builtin_amdgcn_mfma_f32_16x16x32_bf16(xf, wfrag[0], biasf[0], 0, 0, 0);
        accP1 = __builtin_amdgcn_mfma_f32_16x16x32_bf16(xf, wfrag[1], biasf[1], 0, 0, 0);
    }
    #pragma unroll
    for (int tile = 1; tile < 32; ++tile) {
        bf16x8 xf; __builtin_memcpy(&xf, &x_nxt, 16);
        if (tile < 31) x_nxt = im2col[g][(tile + 1) * 16 + lm];
        f32x4 accN0 = __builtin_amdgcn_mfma_f32_16x16x32_bf16(xf, wfrag[0], biasf[0], 0, 0, 0);
        f32x4 accN1 = __builtin_amdgcn_mfma_f32_16x16x32_bf16(xf, wfrag[1], biasf[1], 0, 0, 0);
        #pragma unroll
        for (int r = 0; r < 4; ++r) {
            pool[0][r] += (accP0[r] > LAMBDA) ? accP0[r] : 0.f;  // relu+hardshrink
            pool[1][r] += (accP1[r] > LAMBDA) ? accP1[r] : 0.f;
        }
        accP0 = accN0; accP1 = accN1;
    }
    #pragma unroll
    for (int r = 0; r < 4; ++r) {
        pool[0][r] += (accP0[r] > LAMBDA) ? accP0[r] : 0.f;
        pool[1][r] += (accP1[r] > LAMBDA) ? accP1[r] : 0.f;
    }

    // ---- reduce over px: in-lane fold + xor16 + xor32; partial store ----
    #pragma unroll
    for (int c = 0; c < 2; ++c) {
        float s = (pool[c][0] + pool[c][1]) + (pool[c][2] + pool[c][3]);
        s += __shfl_xor(s, 16, 64);
        s += __shfl_xor(s, 32, 64);
        if (l < 16)
            part[bk * 256 + (wv * 2 + c) * 16 + lm] = s;
    }
}

// ---------------------------------------------------------------------------
// FC: reduce 32 per-block partials -> pooled[b], then
// out[b][d] = log_sigmoid(dot(pooled[b]/16384, fc_w[d]) + fc_b[d])
// ---------------------------------------------------------------------------
__global__ __launch_bounds__(256) void fc_kernel(
    const float* __restrict__ part, const float* __restrict__ fc_w,
    const float* __restrict__ fc_b, float* __restrict__ out)
{
    __shared__ float pool[CMID];
    const int b = blockIdx.y;
    const int t = threadIdx.x;

    float s = 0.f;
    const float* pp = part + b * 32 * 256 + t;
    #pragma unroll
    for (int j = 0; j < 32; ++j) s += pp[j * 256];
    pool[t] = s * (1.0f / 16384.0f);
    __syncthreads();

    const int d = blockIdx.x * 256 + t;
    const float4* wrow = (const float4*)(fc_w + d * CMID);
    float acc = fc_b[d];
    #pragma unroll 8
    for (int k4 = 0; k4 < CMID / 4; k4++) {
        float4 wv = wrow[k4];
        acc += wv.x * pool[k4 * 4 + 0] + wv.y * pool[k4 * 4 + 1]
             + wv.z * pool[k4 * 4 + 2] + wv.w * pool[k4 * 4 + 3];
    }
    float ls = fminf(acc, 0.f) - log1pf(expf(-fabsf(acc)));
    out[b * (int)DOUT + d] = ls;
}

// ---------------------------------------------------------------------------
extern "C" void kernel_launch(void* const* d_in, const int* in_sizes, int n_in,
                              void* d_out, int out_size, void* d_ws, size_t ws_size,
                              hipStream_t stream) {
    const float* x      = (const float*)d_in[0];   // [32,3,128,128]
    const float* conv_w = (const float*)d_in[1];   // [256,3,3,3]
    const float* conv_b = (const float*)d_in[2];   // [256]
    const float* fc_w   = (const float*)d_in[3];   // [4096,256]
    const float* fc_b   = (const float*)d_in[4];   // [4096]
    float* out = (float*)d_out;                    // [32,4096]

    float* part = (float*)d_ws;                    // [1024][256] = 1 MB partials

    conv_pool_mfma<<<32 * 32, 512, 0, stream>>>(x, conv_w, conv_b, part);
    fc_kernel<<<dim3(16, 32), 256, 0, stream>>>(part, fc_w, fc_b, out);
}